// Round 6
// baseline (393.429 us; speedup 1.0000x reference)
//
#include <hip/hip_runtime.h>

// ---------------------------------------------------------------------------
// SpatialSatCrossAttention (MS deformable attention, 6 cams, 10000 queries)
// ALL float tensors are float32 on the wire; vox int32.
// Launches (4):
//   1. prep_k    : value->bf16, query->bf16, 4 weight mats -> Wt[n][k] bf16
//   2. gemm_two  : vproj = value_bf @ value_W + b   (bf16, 510 blocks)   and
//                  qkcat = query_bf @ [off|attw]_W  (f32, 474 blocks) fused
//   3. sample_k  : deformable bilinear sampling -> slots bf16
//   4. gemm_out  : out = slots @ out_W + out_b + query (f32 d_out)
// GEMM body: 128x128 tile, 4 waves (2x2), 4x4 mfma_f32_16x16x32_bf16, BK=32,
// double-buffered LDS + register prefetch.
// ---------------------------------------------------------------------------

typedef unsigned short ushort_t;
typedef unsigned int uint_t;
typedef __attribute__((ext_vector_type(8))) short bf16x8;
typedef __attribute__((ext_vector_type(4))) float f32x4;
typedef __attribute__((ext_vector_type(2))) float f32x2;

__device__ __forceinline__ float bf2f(ushort_t u) {
    return __uint_as_float(((uint_t)u) << 16);
}
__device__ __forceinline__ ushort_t f2bf(float f) {
    uint_t i = __float_as_uint(f);
    uint_t r = i + 0x7fffu + ((i >> 16) & 1u);   // round-to-nearest-even
    return (ushort_t)(r >> 16);
}

// ---------------------------------------------------------------------------
// prep_k: fused elementwise cvt (value, query) + weight transpose+convert.
// grid 5842 x 256:
//   [0,4080)    : value f32 -> bf16, 8 elems/thread
//   [4080,5330) : query f32 -> bf16
//   [5330,5842) : transpose W[k][N] -> T[n][256] bf16 (z = (b-5330)/128)
// ---------------------------------------------------------------------------
__global__ __launch_bounds__(256) void prep_k(
    const float* __restrict__ value, const float* __restrict__ query,
    const float* __restrict__ Wv, const float* __restrict__ Wo,
    const float* __restrict__ Wf, const float* __restrict__ Wa,
    ushort_t* __restrict__ value_bf, ushort_t* __restrict__ query_bf,
    ushort_t* __restrict__ Tv, ushort_t* __restrict__ To,
    ushort_t* __restrict__ Tqk) {
    __shared__ float tile[32][33];
    const int b = blockIdx.x;
    const int tid = threadIdx.x;

    if (b < 5330) {
        const float* src;
        ushort_t* dst;
        int i, n8;
        if (b < 4080) { src = value; dst = value_bf; i = b * 256 + tid;           n8 = 1044480; }
        else          { src = query; dst = query_bf; i = (b - 4080) * 256 + tid;  n8 = 320000; }
        if (i >= n8) return;
        const float4 v0 = *(const float4*)(src + (size_t)i * 8);
        const float4 v1 = *(const float4*)(src + (size_t)i * 8 + 4);
        const bf16x8 pk = {
            (short)f2bf(v0.x), (short)f2bf(v0.y), (short)f2bf(v0.z), (short)f2bf(v0.w),
            (short)f2bf(v1.x), (short)f2bf(v1.y), (short)f2bf(v1.z), (short)f2bf(v1.w)};
        *(bf16x8*)(dst + (size_t)i * 8) = pk;
        return;
    }

    // ---- transpose branch ----
    const int b2 = b - 5330;
    const int z   = b2 >> 7;
    const int rem = b2 & 127;
    const int k0 = (rem & 7) * 32;
    const int n0 = (rem >> 3) * 32;
    const float* W;
    ushort_t* T;
    int N;
    if (z == 0)      { W = Wv; T = Tv;              N = 256; }
    else if (z == 1) { W = Wo; T = To;              N = 256; }
    else if (z == 2) { W = Wf; T = Tqk;             N = 512; }
    else             { W = Wa; T = Tqk + 512 * 256; N = 256; }
    if (n0 >= N) return;

    const int tx = tid & 31;
    const int ty = tid >> 5;   // 0..7
    #pragma unroll
    for (int r = 0; r < 4; ++r) {
        const int k = ty + r * 8;
        tile[k][tx] = W[(size_t)(k0 + k) * N + n0 + tx];
    }
    __syncthreads();
    #pragma unroll
    for (int r = 0; r < 4; ++r) {
        const int n = ty + r * 8;
        T[(size_t)(n0 + n) * 256 + k0 + tx] = f2bf(tile[tx][n]);
    }
}

// ---------------------------------------------------------------------------
// Shared MFMA GEMM body: C[M,N] = A[M,256] @ Wt^T + bias (+resid).
// A bf16 [M][256]; Wt bf16 [N][256]. N multiple of 128. 256 threads.
// ---------------------------------------------------------------------------
struct GemmSmem {
    ushort_t sA[2][128][32];
    ushort_t sB[2][128][32];
};

__device__ __forceinline__ void gemm_body(
    GemmSmem* sm,
    const ushort_t* __restrict__ A, const ushort_t* __restrict__ Wt,
    const float* __restrict__ bias0, const float* __restrict__ bias1, int split,
    const float* __restrict__ resid, void* __restrict__ Cv, int M, int N,
    bool out_bf16, int bx, int by) {
    const int m0 = bx * 128;
    const int n0 = by * 128;
    const int t    = threadIdx.x;
    const int lane = t & 63;
    const int w    = t >> 6;
    const int wr   = w >> 1, wc = w & 1;

    const int srow = t >> 2;          // 0..63
    const int skof = (t & 3) * 8;     // 0,8,16,24

    const bool am0 = (m0 + srow) < M;
    const bool am1 = (m0 + 64 + srow) < M;
    const ushort_t* Ap0 = A + (size_t)(m0 + srow) * 256 + skof;
    const ushort_t* Ap1 = Ap0 + (size_t)64 * 256;
    const ushort_t* Bp0 = Wt + (size_t)(n0 + srow) * 256 + skof;
    const ushort_t* Bp1 = Bp0 + (size_t)64 * 256;

    f32x4 acc[4][4];
    #pragma unroll
    for (int i = 0; i < 4; ++i)
        #pragma unroll
        for (int j = 0; j < 4; ++j)
            acc[i][j] = (f32x4){0.f, 0.f, 0.f, 0.f};

    const bf16x8 zz = {0, 0, 0, 0, 0, 0, 0, 0};

    // prologue: tile 0 -> LDS[0]
    {
        const bf16x8 a0 = am0 ? *(const bf16x8*)(Ap0) : zz;
        const bf16x8 a1 = am1 ? *(const bf16x8*)(Ap1) : zz;
        const bf16x8 b0 = *(const bf16x8*)(Bp0);
        const bf16x8 b1 = *(const bf16x8*)(Bp1);
        *(bf16x8*)(&sm->sA[0][srow][skof])      = a0;
        *(bf16x8*)(&sm->sA[0][64 + srow][skof]) = a1;
        *(bf16x8*)(&sm->sB[0][srow][skof])      = b0;
        *(bf16x8*)(&sm->sB[0][64 + srow][skof]) = b1;
    }
    __syncthreads();

    const int rl = lane & 15;
    const int kq = (lane >> 4) * 8;

    for (int k = 0; k < 8; ++k) {
        const int buf = k & 1;

        bf16x8 na0 = zz, na1 = zz, nb0 = zz, nb1 = zz;
        if (k < 7) {
            const int ko = (k + 1) * 32;
            if (am0) na0 = *(const bf16x8*)(Ap0 + ko);
            if (am1) na1 = *(const bf16x8*)(Ap1 + ko);
            nb0 = *(const bf16x8*)(Bp0 + ko);
            nb1 = *(const bf16x8*)(Bp1 + ko);
        }

        bf16x8 af[4], bfr[4];
        #pragma unroll
        for (int i = 0; i < 4; ++i)
            af[i] = *(const bf16x8*)(&sm->sA[buf][wr * 64 + i * 16 + rl][kq]);
        #pragma unroll
        for (int j = 0; j < 4; ++j)
            bfr[j] = *(const bf16x8*)(&sm->sB[buf][wc * 64 + j * 16 + rl][kq]);
        #pragma unroll
        for (int i = 0; i < 4; ++i)
            #pragma unroll
            for (int j = 0; j < 4; ++j)
                acc[i][j] = __builtin_amdgcn_mfma_f32_16x16x32_bf16(
                    af[i], bfr[j], acc[i][j], 0, 0, 0);

        if (k < 7) {
            __syncthreads();
            *(bf16x8*)(&sm->sA[buf ^ 1][srow][skof])      = na0;
            *(bf16x8*)(&sm->sA[buf ^ 1][64 + srow][skof]) = na1;
            *(bf16x8*)(&sm->sB[buf ^ 1][srow][skof])      = nb0;
            *(bf16x8*)(&sm->sB[buf ^ 1][64 + srow][skof]) = nb1;
            __syncthreads();
        }
    }

    // --- epilogue: C/D layout col=lane&15, row=(lane>>4)*4+reg (m89) ---
    const int col_l = lane & 15;
    const int rq    = (lane >> 4) * 4;
    #pragma unroll
    for (int j = 0; j < 4; ++j) {
        const int gn = n0 + wc * 64 + j * 16 + col_l;
        const float bj = (gn < split) ? bias0[gn] : bias1[gn - split];
        #pragma unroll
        for (int i = 0; i < 4; ++i) {
            #pragma unroll
            for (int r = 0; r < 4; ++r) {
                const int gm = m0 + wr * 64 + i * 16 + rq + r;
                if (gm >= M) continue;
                float v = acc[i][j][r] + bj;
                if (resid) v += resid[(size_t)gm * N + gn];
                if (out_bf16)
                    ((ushort_t*)Cv)[(size_t)gm * N + gn] = f2bf(v);
                else
                    ((float*)Cv)[(size_t)gm * N + gn] = v;
            }
        }
    }
}

// Fused independent GEMMs: blocks [0,510) -> vproj, [510,984) -> qkcat.
__global__ __launch_bounds__(256) void gemm_two(
    const ushort_t* __restrict__ value_bf, const ushort_t* __restrict__ value_Wt,
    const float* __restrict__ value_b, ushort_t* __restrict__ vproj,
    const ushort_t* __restrict__ query_bf, const ushort_t* __restrict__ qk_Wt,
    const float* __restrict__ off_b, const float* __restrict__ attw_b,
    float* __restrict__ qkcat) {
    __shared__ GemmSmem sm;
    int b = blockIdx.x;
    const ushort_t *A, *Wt;
    const float *b0, *b1;
    int split, M, N, bx, by;
    bool obf;
    void* Cv;
    if (b < 510) {
        A = value_bf; Wt = value_Wt; b0 = value_b; b1 = value_b; split = 256;
        M = 32640; N = 256; obf = true; Cv = (void*)vproj;
        bx = b % 255; by = b / 255;
    } else {
        b -= 510;
        A = query_bf; Wt = qk_Wt; b0 = off_b; b1 = attw_b; split = 512;
        M = 10000; N = 768; obf = false; Cv = (void*)qkcat;
        bx = b % 79; by = b / 79;
    }
    gemm_body(&sm, A, Wt, b0, b1, split, nullptr, Cv, M, N, obf, bx, by);
}

__global__ __launch_bounds__(256) void gemm_out_k(
    const ushort_t* __restrict__ slots, const ushort_t* __restrict__ out_Wt,
    const float* __restrict__ out_b, const float* __restrict__ query,
    float* __restrict__ out) {
    __shared__ GemmSmem sm;
    gemm_body(&sm, slots, out_Wt, out_b, out_b, 256, query, (void*)out,
              10000, 256, false, blockIdx.x, blockIdx.y);
}

// ---------------------------------------------------------------------------
// Deformable sampling. 1 block per query, 256 threads.
//   setup role : (h, lp = tid&31)  -> corner idx/weights for its (h,lvl,p)
//   gather role: (h, slice, g)     -> 16B dwordx4 loads of 8 bf16 channels
// Corner (idx,w) packed: s_iw[el][0]={i0,w0,i1,w1}, [1]={i2,w2,i3,w3}
// -> 2x ds_read_b128 per j-iter.  Accumulate in float2 (v_pk_fma_f32).
// ---------------------------------------------------------------------------
__global__ __launch_bounds__(256) void sample_k(
    const float* __restrict__ qkcat,    // [10000, 768]
    const float* __restrict__ refp,     // f32 [6,1,10000,4,2]
    const int* __restrict__ vox,        // int32 [6,1,10000,4]
    const ushort_t* __restrict__ vproj, // bf16 [6*5440, 256]
    ushort_t* __restrict__ slots) {     // bf16 [10000, 256]
    const int q   = blockIdx.x;
    const int tid = threadIdx.x;
    const int h     = tid >> 5;
    const int lp    = tid & 31;          // setup role
    const int slice = (tid >> 2) & 7;    // gather role
    const int g     = tid & 3;           // gather role: channels g*8..g*8+7

    __shared__ float s_valid[8];
    __shared__ int4  s_iw[256][2];       // [el][half]: {idx,w,idx,w}
    __shared__ float s_red[256][8];      // [tid][chan-in-group]

    if (tid < 6) {
        const int base = (tid * 10000 + q) * 4;
        const int mm = vox[base] | vox[base + 1] | vox[base + 2] | vox[base + 3];
        s_valid[tid] = mm ? 1.0f : 0.0f;
    }

    // ---- softmax over 32 (lvl,p) entries within each head ----
    const float a = qkcat[(size_t)q * 768 + 512 + tid];
    float mx = a;
    #pragma unroll
    for (int o = 16; o >= 1; o >>= 1) mx = fmaxf(mx, __shfl_xor(mx, o));
    const float e = __expf(a - mx);
    float se = e;
    #pragma unroll
    for (int o = 16; o >= 1; o >>= 1) se += __shfl_xor(se, o);
    const float aw = e / se;

    // ---- camera-independent part of this thread's sample location ----
    const int lvl = lp >> 3;
    const int p   = lp & 7;
    const int dd  = p & 3;
    const int   Sarr[4]   = {64, 32, 16, 8};
    const int   Lstart[4] = {0, 4096, 5120, 5376};
    const int   S  = Sarr[lvl];
    const float Sf = (float)S;
    const int   lstart = Lstart[lvl];
    const float ox = qkcat[(size_t)q * 768 + h * 64 + lvl * 16 + p * 2 + 0] / Sf;
    const float oy = qkcat[(size_t)q * 768 + h * 64 + lvl * 16 + p * 2 + 1] / Sf;

    __syncthreads();
    const float cnt = s_valid[0] + s_valid[1] + s_valid[2] +
                      s_valid[3] + s_valid[4] + s_valid[5];

    f32x2 acc2[4] = {{0.f, 0.f}, {0.f, 0.f}, {0.f, 0.f}, {0.f, 0.f}};
    const int gofs = g << 3;

    for (int c = 0; c < 6; ++c) {
        if (s_valid[c] == 0.0f) continue;   // block-uniform branch

        // ---- setup: this (h,lvl,p) sample's 4 corner (idx, weight) ----
        {
            const int rbase = ((c * 10000 + q) * 4 + dd) * 2;
            const float rx = refp[rbase + 0];
            const float ry = refp[rbase + 1];
            const float x  = (rx + ox) * Sf - 0.5f;
            const float y  = (ry + oy) * Sf - 0.5f;
            const float x0 = floorf(x), y0 = floorf(y);
            int   ci[4];
            float cw[4];
            #pragma unroll
            for (int k = 0; k < 4; ++k) {
                const float cx = x0 + (float)(k & 1);
                const float cy = y0 + (float)(k >> 1);
                const float wgt = (1.0f - fabsf(x - cx)) * (1.0f - fabsf(y - cy));
                const bool ok = (cx >= 0.0f) & (cx < Sf) & (cy >= 0.0f) & (cy < Sf);
                const int xi = (int)fminf(fmaxf(cx, 0.0f), Sf - 1.0f);
                const int yi = (int)fminf(fmaxf(cy, 0.0f), Sf - 1.0f);
                ci[k] = (c * 5440 + lstart + yi * S + xi) * 256 + h * 32;
                cw[k] = ok ? wgt * aw : 0.0f;
            }
            s_iw[tid][0] = make_int4(ci[0], __float_as_int(cw[0]),
                                     ci[1], __float_as_int(cw[1]));
            s_iw[tid][1] = make_int4(ci[2], __float_as_int(cw[2]),
                                     ci[3], __float_as_int(cw[3]));
        }
        __syncthreads();

        // ---- gather: 4 lp x 4 corners, 16B (8 bf16 chans) per load ----
        #pragma unroll
        for (int j = 0; j < 4; ++j) {
            const int el = h * 32 + slice * 4 + j;
            const int4 iw0 = s_iw[el][0];
            const int4 iw1 = s_iw[el][1];
            const int   idx[4] = {iw0.x, iw0.z, iw1.x, iw1.z};
            const float wv[4]  = {__int_as_float(iw0.y), __int_as_float(iw0.w),
                                  __int_as_float(iw1.y), __int_as_float(iw1.w)};
            #pragma unroll
            for (int k = 0; k < 4; ++k) {
                const f32x2 w2 = {wv[k], wv[k]};
                const uint4 v = *(const uint4*)(vproj + idx[k] + gofs);
                f32x2 p0 = {__uint_as_float(v.x << 16),
                            __uint_as_float(v.x & 0xffff0000u)};
                f32x2 p1 = {__uint_as_float(v.y << 16),
                            __uint_as_float(v.y & 0xffff0000u)};
                f32x2 p2 = {__uint_as_float(v.z << 16),
                            __uint_as_float(v.z & 0xffff0000u)};
                f32x2 p3 = {__uint_as_float(v.w << 16),
                            __uint_as_float(v.w & 0xffff0000u)};
                acc2[0] += w2 * p0;
                acc2[1] += w2 * p1;
                acc2[2] += w2 * p2;
                acc2[3] += w2 * p3;
            }
        }
        __syncthreads();
    }

    // ---- cross-slice reduction ----
    #pragma unroll
    for (int n = 0; n < 4; ++n) {
        s_red[tid][2 * n]     = acc2[n].x;
        s_red[tid][2 * n + 1] = acc2[n].y;
    }
    __syncthreads();

    const int cch = tid & 31;
    float sum = 0.0f;
    #pragma unroll
    for (int s = 0; s < 8; ++s)
        sum += s_red[h * 32 + s * 4 + (cch >> 3)][cch & 7];

    slots[(size_t)q * 256 + tid] = f2bf(sum / fmaxf(cnt, 1.0f));
}

// ---------------------------------------------------------------------------
extern "C" void kernel_launch(void* const* d_in, const int* in_sizes, int n_in,
                              void* d_out, int out_size, void* d_ws, size_t ws_size,
                              hipStream_t stream) {
    const float* query   = (const float*)d_in[0];
    // d_in[1] = key : unused by the deformable-attention math
    const float* value   = (const float*)d_in[2];   // (6,5440,1,256) -> (32640,256)
    const float* refp    = (const float*)d_in[3];
    const int*   vox     = (const int*)d_in[4];
    // d_in[5] spatial_shapes, d_in[6] level_start_index : compile-time constants
    const float* value_W = (const float*)d_in[7];
    const float* value_b = (const float*)d_in[8];
    const float* off_W   = (const float*)d_in[9];
    const float* off_b   = (const float*)d_in[10];
    const float* attw_W  = (const float*)d_in[11];
    const float* attw_b  = (const float*)d_in[12];
    const float* out_W   = (const float*)d_in[13];
    const float* out_b   = (const float*)d_in[14];
    float* out = (float*)d_out;

    // ws layout (bytes), liveness-aliased:
    //   [0, 16711680)        vproj bf16 [32640][256]
    //   [16711680, 47431680) value_bf bf16 (dead after gemm_two) / qkcat f32
    //   [47431680, 52551680) query_bf bf16 (dead after gemm_two) / slots bf16
    //   [52551680, ...)      value_Wt | out_Wt | qk_Wt  bf16
    char* ws = (char*)d_ws;
    ushort_t* vproj    = (ushort_t*)ws;
    ushort_t* value_bf = (ushort_t*)(ws + 16711680);
    float*    qkcat    = (float*)   (ws + 16711680);
    ushort_t* query_bf = (ushort_t*)(ws + 47431680);
    ushort_t* slots    = (ushort_t*)(ws + 47431680);
    ushort_t* value_Wt = (ushort_t*)(ws + 52551680);
    ushort_t* out_Wt   = (ushort_t*)(ws + 52551680 + 131072);
    ushort_t* qk_Wt    = (ushort_t*)(ws + 52551680 + 262144);

    // 1. prep: cvt value/query to bf16 + transpose/convert all weights
    prep_k<<<5842, 256, 0, stream>>>(value, query, value_W, out_W, off_W, attw_W,
                                     value_bf, query_bf, value_Wt, out_Wt, qk_Wt);
    // 2. fused value-proj (bf16 out) + offset/attw-proj (f32 out)
    gemm_two<<<984, 256, 0, stream>>>(value_bf, value_Wt, value_b, vproj,
                                      query_bf, qk_Wt, off_b, attw_b, qkcat);
    // 3. deformable sampling + softmax + camera mask/count -> bf16 slots
    sample_k<<<10000, 256, 0, stream>>>(qkcat, refp, vox, vproj, slots);
    // 4. output projection + residual, f32 out
    gemm_out_k<<<dim3(79, 2), 256, 0, stream>>>(slots, out_Wt, out_b, query, out);
}

// Round 7
// 337.778 us; speedup vs baseline: 1.1648x; 1.1648x over previous
//
#include <hip/hip_runtime.h>

// ---------------------------------------------------------------------------
// SpatialSatCrossAttention (MS deformable attention, 6 cams, 10000 queries)
// ALL float tensors are float32 on the wire; vox int32.
// Launches (5):
//   1. prep_k           : value->bf16, query->bf16, weights -> Wt[n][k] bf16
//   2. gemm_mfma<bf16>  : vproj = value_bf @ value_W + b      (bf16, ws)
//   3. gemm_mfma        : qkcat = query_bf @ [off|attw]_W     (f32, ws, N=768)
//   4. sample_k         : deformable bilinear sampling -> slots bf16
//   5. gemm_mfma<resid> : out = slots @ out_W + out_b + query (f32 d_out)
// GEMM: 128x128 tile, 4 waves (2x2), 4x4 mfma_f32_16x16x32_bf16, BK=32,
// double-buffered LDS + register prefetch.
// sample_k: R5 LDS layout (s_ci/s_cw planes, conflict-free) + batched
// 4-corner register loads + f32x2 packed accumulate (v_pk_fma_f32).
// ---------------------------------------------------------------------------

typedef unsigned short ushort_t;
typedef unsigned int uint_t;
typedef __attribute__((ext_vector_type(8))) short bf16x8;
typedef __attribute__((ext_vector_type(4))) float f32x4;
typedef __attribute__((ext_vector_type(2))) float f32x2;

__device__ __forceinline__ float bf2f(ushort_t u) {
    return __uint_as_float(((uint_t)u) << 16);
}
__device__ __forceinline__ ushort_t f2bf(float f) {
    uint_t i = __float_as_uint(f);
    uint_t r = i + 0x7fffu + ((i >> 16) & 1u);   // round-to-nearest-even
    return (ushort_t)(r >> 16);
}

// ---------------------------------------------------------------------------
// prep_k: fused elementwise cvt (value, query) + weight transpose+convert.
// grid 5842 x 256:
//   [0,4080)    : value f32 -> bf16, 8 elems/thread
//   [4080,5330) : query f32 -> bf16
//   [5330,5842) : transpose W[k][N] -> T[n][256] bf16 (z = (b-5330)/128)
// ---------------------------------------------------------------------------
__global__ __launch_bounds__(256) void prep_k(
    const float* __restrict__ value, const float* __restrict__ query,
    const float* __restrict__ Wv, const float* __restrict__ Wo,
    const float* __restrict__ Wf, const float* __restrict__ Wa,
    ushort_t* __restrict__ value_bf, ushort_t* __restrict__ query_bf,
    ushort_t* __restrict__ Tv, ushort_t* __restrict__ To,
    ushort_t* __restrict__ Tqk) {
    __shared__ float tile[32][33];
    const int b = blockIdx.x;
    const int tid = threadIdx.x;

    if (b < 5330) {
        const float* src;
        ushort_t* dst;
        int i, n8;
        if (b < 4080) { src = value; dst = value_bf; i = b * 256 + tid;           n8 = 1044480; }
        else          { src = query; dst = query_bf; i = (b - 4080) * 256 + tid;  n8 = 320000; }
        if (i >= n8) return;
        const float4 v0 = *(const float4*)(src + (size_t)i * 8);
        const float4 v1 = *(const float4*)(src + (size_t)i * 8 + 4);
        const bf16x8 pk = {
            (short)f2bf(v0.x), (short)f2bf(v0.y), (short)f2bf(v0.z), (short)f2bf(v0.w),
            (short)f2bf(v1.x), (short)f2bf(v1.y), (short)f2bf(v1.z), (short)f2bf(v1.w)};
        *(bf16x8*)(dst + (size_t)i * 8) = pk;
        return;
    }

    // ---- transpose branch ----
    const int b2 = b - 5330;
    const int z   = b2 >> 7;
    const int rem = b2 & 127;
    const int k0 = (rem & 7) * 32;
    const int n0 = (rem >> 3) * 32;
    const float* W;
    ushort_t* T;
    int N;
    if (z == 0)      { W = Wv; T = Tv;              N = 256; }
    else if (z == 1) { W = Wo; T = To;              N = 256; }
    else if (z == 2) { W = Wf; T = Tqk;             N = 512; }
    else             { W = Wa; T = Tqk + 512 * 256; N = 256; }
    if (n0 >= N) return;

    const int tx = tid & 31;
    const int ty = tid >> 5;   // 0..7
    #pragma unroll
    for (int r = 0; r < 4; ++r) {
        const int k = ty + r * 8;
        tile[k][tx] = W[(size_t)(k0 + k) * N + n0 + tx];
    }
    __syncthreads();
    #pragma unroll
    for (int r = 0; r < 4; ++r) {
        const int n = ty + r * 8;
        T[(size_t)(n0 + n) * 256 + k0 + tx] = f2bf(tile[tx][n]);
    }
}

// ---------------------------------------------------------------------------
// MFMA GEMM (templated): C[M,N] = A[M,256] @ Wt^T + bias (+resid).
// A bf16 [M][256]; Wt bf16 [N][256]. N multiple of 128.
// bias: f32, column gn takes bias0[gn] if gn<split else bias1[gn-split].
// Double-buffered LDS, register prefetch of next K-tile.
// ---------------------------------------------------------------------------
template <bool OUT_BF16, bool RESID>
__global__ __launch_bounds__(256) void gemm_mfma(
    const ushort_t* __restrict__ A, const ushort_t* __restrict__ Wt,
    const float* __restrict__ bias0, const float* __restrict__ bias1, int split,
    const float* __restrict__ resid, void* __restrict__ Cv, int M, int N) {
    __shared__ ushort_t sA[2][128][32];
    __shared__ ushort_t sB[2][128][32];

    const int m0 = blockIdx.x * 128;
    const int n0 = blockIdx.y * 128;
    const int t    = threadIdx.x;
    const int lane = t & 63;
    const int w    = t >> 6;
    const int wr   = w >> 1, wc = w & 1;

    const int srow = t >> 2;          // 0..63
    const int skof = (t & 3) * 8;     // 0,8,16,24

    const bool am0 = (m0 + srow) < M;
    const bool am1 = (m0 + 64 + srow) < M;
    const ushort_t* Ap0 = A + (size_t)(m0 + srow) * 256 + skof;
    const ushort_t* Ap1 = Ap0 + (size_t)64 * 256;
    const ushort_t* Bp0 = Wt + (size_t)(n0 + srow) * 256 + skof;
    const ushort_t* Bp1 = Bp0 + (size_t)64 * 256;

    f32x4 acc[4][4];
    #pragma unroll
    for (int i = 0; i < 4; ++i)
        #pragma unroll
        for (int j = 0; j < 4; ++j)
            acc[i][j] = (f32x4){0.f, 0.f, 0.f, 0.f};

    const bf16x8 zz = {0, 0, 0, 0, 0, 0, 0, 0};

    // prologue: tile 0 -> LDS[0]
    {
        const bf16x8 a0 = am0 ? *(const bf16x8*)(Ap0) : zz;
        const bf16x8 a1 = am1 ? *(const bf16x8*)(Ap1) : zz;
        const bf16x8 b0 = *(const bf16x8*)(Bp0);
        const bf16x8 b1 = *(const bf16x8*)(Bp1);
        *(bf16x8*)(&sA[0][srow][skof])      = a0;
        *(bf16x8*)(&sA[0][64 + srow][skof]) = a1;
        *(bf16x8*)(&sB[0][srow][skof])      = b0;
        *(bf16x8*)(&sB[0][64 + srow][skof]) = b1;
    }
    __syncthreads();

    const int rl = lane & 15;
    const int kq = (lane >> 4) * 8;

    for (int k = 0; k < 8; ++k) {
        const int buf = k & 1;

        bf16x8 na0 = zz, na1 = zz, nb0 = zz, nb1 = zz;
        if (k < 7) {
            const int ko = (k + 1) * 32;
            if (am0) na0 = *(const bf16x8*)(Ap0 + ko);
            if (am1) na1 = *(const bf16x8*)(Ap1 + ko);
            nb0 = *(const bf16x8*)(Bp0 + ko);
            nb1 = *(const bf16x8*)(Bp1 + ko);
        }

        bf16x8 af[4], bfr[4];
        #pragma unroll
        for (int i = 0; i < 4; ++i)
            af[i] = *(const bf16x8*)(&sA[buf][wr * 64 + i * 16 + rl][kq]);
        #pragma unroll
        for (int j = 0; j < 4; ++j)
            bfr[j] = *(const bf16x8*)(&sB[buf][wc * 64 + j * 16 + rl][kq]);
        #pragma unroll
        for (int i = 0; i < 4; ++i)
            #pragma unroll
            for (int j = 0; j < 4; ++j)
                acc[i][j] = __builtin_amdgcn_mfma_f32_16x16x32_bf16(
                    af[i], bfr[j], acc[i][j], 0, 0, 0);

        if (k < 7) {
            __syncthreads();
            *(bf16x8*)(&sA[buf ^ 1][srow][skof])      = na0;
            *(bf16x8*)(&sA[buf ^ 1][64 + srow][skof]) = na1;
            *(bf16x8*)(&sB[buf ^ 1][srow][skof])      = nb0;
            *(bf16x8*)(&sB[buf ^ 1][64 + srow][skof]) = nb1;
            __syncthreads();
        }
    }

    // --- epilogue: C/D layout col=lane&15, row=(lane>>4)*4+reg (m89) ---
    const int col_l = lane & 15;
    const int rq    = (lane >> 4) * 4;
    #pragma unroll
    for (int j = 0; j < 4; ++j) {
        const int gn = n0 + wc * 64 + j * 16 + col_l;
        const float bj = (gn < split) ? bias0[gn] : bias1[gn - split];
        #pragma unroll
        for (int i = 0; i < 4; ++i) {
            #pragma unroll
            for (int r = 0; r < 4; ++r) {
                const int gm = m0 + wr * 64 + i * 16 + rq + r;
                if (gm >= M) continue;
                float v = acc[i][j][r] + bj;
                if (RESID) v += resid[(size_t)gm * N + gn];
                if (OUT_BF16)
                    ((ushort_t*)Cv)[(size_t)gm * N + gn] = f2bf(v);
                else
                    ((float*)Cv)[(size_t)gm * N + gn] = v;
            }
        }
    }
}

// ---------------------------------------------------------------------------
// Deformable sampling. 1 block per query, 256 threads.
//   setup role : (h, lp = tid&31)  -> corner idx/weights for its (h,lvl,p)
//   gather role: (h, slice, g)     -> 16B dwordx4 loads of 8 bf16 channels
// Corner tables in conflict-free planes s_ci[4][256]/s_cw[4][256].
// All 4 corner loads batched into registers before consuming (MLP),
// f32x2 accumulators (v_pk_fma_f32 halves FMA issue count).
// ---------------------------------------------------------------------------
__global__ __launch_bounds__(256) void sample_k(
    const float* __restrict__ qkcat,    // [10000, 768]
    const float* __restrict__ refp,     // f32 [6,1,10000,4,2]
    const int* __restrict__ vox,        // int32 [6,1,10000,4]
    const ushort_t* __restrict__ vproj, // bf16 [6*5440, 256]
    ushort_t* __restrict__ slots) {     // bf16 [10000, 256]
    const int q   = blockIdx.x;
    const int tid = threadIdx.x;
    const int h     = tid >> 5;
    const int lp    = tid & 31;          // setup role
    const int slice = (tid >> 2) & 7;    // gather role
    const int g     = tid & 3;           // gather role: channels g*8..g*8+7

    __shared__ float s_valid[8];
    __shared__ int   s_ci[4][256];       // [corner][h*32+lp]
    __shared__ float s_cw[4][256];
    __shared__ float s_red[256][8];      // [tid][chan-in-group]

    if (tid < 6) {
        const int base = (tid * 10000 + q) * 4;
        const int mm = vox[base] | vox[base + 1] | vox[base + 2] | vox[base + 3];
        s_valid[tid] = mm ? 1.0f : 0.0f;
    }

    // ---- softmax over 32 (lvl,p) entries within each head ----
    const float a = qkcat[(size_t)q * 768 + 512 + tid];
    float mx = a;
    #pragma unroll
    for (int o = 16; o >= 1; o >>= 1) mx = fmaxf(mx, __shfl_xor(mx, o));
    const float e = __expf(a - mx);
    float se = e;
    #pragma unroll
    for (int o = 16; o >= 1; o >>= 1) se += __shfl_xor(se, o);
    const float aw = e / se;

    // ---- camera-independent part of this thread's sample location ----
    const int lvl = lp >> 3;
    const int p   = lp & 7;
    const int dd  = p & 3;
    const int   Sarr[4]   = {64, 32, 16, 8};
    const int   Lstart[4] = {0, 4096, 5120, 5376};
    const int   S  = Sarr[lvl];
    const float Sf = (float)S;
    const int   lstart = Lstart[lvl];
    const float ox = qkcat[(size_t)q * 768 + h * 64 + lvl * 16 + p * 2 + 0] / Sf;
    const float oy = qkcat[(size_t)q * 768 + h * 64 + lvl * 16 + p * 2 + 1] / Sf;

    __syncthreads();
    const float cnt = s_valid[0] + s_valid[1] + s_valid[2] +
                      s_valid[3] + s_valid[4] + s_valid[5];

    f32x2 acc2[4] = {{0.f, 0.f}, {0.f, 0.f}, {0.f, 0.f}, {0.f, 0.f}};
    const ushort_t* vp = vproj + (g << 3);   // per-thread channel-group base

    for (int c = 0; c < 6; ++c) {
        if (s_valid[c] == 0.0f) continue;   // block-uniform branch

        // ---- setup: this (h,lvl,p) sample's 4 corner indices + weights ----
        {
            const int rbase = ((c * 10000 + q) * 4 + dd) * 2;
            const float rx = refp[rbase + 0];
            const float ry = refp[rbase + 1];
            const float x  = (rx + ox) * Sf - 0.5f;
            const float y  = (ry + oy) * Sf - 0.5f;
            const float x0 = floorf(x), y0 = floorf(y);
            #pragma unroll
            for (int k = 0; k < 4; ++k) {
                const float cx = x0 + (float)(k & 1);
                const float cy = y0 + (float)(k >> 1);
                const float wgt = (1.0f - fabsf(x - cx)) * (1.0f - fabsf(y - cy));
                const bool ok = (cx >= 0.0f) & (cx < Sf) & (cy >= 0.0f) & (cy < Sf);
                const int xi = (int)fminf(fmaxf(cx, 0.0f), Sf - 1.0f);
                const int yi = (int)fminf(fmaxf(cy, 0.0f), Sf - 1.0f);
                s_ci[k][tid] = (c * 5440 + lstart + yi * S + xi) * 256 + h * 32;
                s_cw[k][tid] = ok ? wgt * aw : 0.0f;
            }
        }
        __syncthreads();

        // ---- gather: 4 lp x 4 corners; batch all 4 16B loads, then math ----
        #pragma unroll
        for (int j = 0; j < 4; ++j) {
            const int el = h * 32 + slice * 4 + j;
            const int i0 = s_ci[0][el], i1 = s_ci[1][el];
            const int i2 = s_ci[2][el], i3 = s_ci[3][el];
            const float w0 = s_cw[0][el], w1 = s_cw[1][el];
            const float w2 = s_cw[2][el], w3 = s_cw[3][el];
            const uint4 v0 = *(const uint4*)(vp + i0);
            const uint4 v1 = *(const uint4*)(vp + i1);
            const uint4 v2 = *(const uint4*)(vp + i2);
            const uint4 v3 = *(const uint4*)(vp + i3);
            const f32x2 W0 = {w0, w0}, W1 = {w1, w1}, W2 = {w2, w2}, W3 = {w3, w3};
            acc2[0] += W0 * (f32x2){__uint_as_float(v0.x << 16),
                                    __uint_as_float(v0.x & 0xffff0000u)};
            acc2[1] += W0 * (f32x2){__uint_as_float(v0.y << 16),
                                    __uint_as_float(v0.y & 0xffff0000u)};
            acc2[2] += W0 * (f32x2){__uint_as_float(v0.z << 16),
                                    __uint_as_float(v0.z & 0xffff0000u)};
            acc2[3] += W0 * (f32x2){__uint_as_float(v0.w << 16),
                                    __uint_as_float(v0.w & 0xffff0000u)};
            acc2[0] += W1 * (f32x2){__uint_as_float(v1.x << 16),
                                    __uint_as_float(v1.x & 0xffff0000u)};
            acc2[1] += W1 * (f32x2){__uint_as_float(v1.y << 16),
                                    __uint_as_float(v1.y & 0xffff0000u)};
            acc2[2] += W1 * (f32x2){__uint_as_float(v1.z << 16),
                                    __uint_as_float(v1.z & 0xffff0000u)};
            acc2[3] += W1 * (f32x2){__uint_as_float(v1.w << 16),
                                    __uint_as_float(v1.w & 0xffff0000u)};
            acc2[0] += W2 * (f32x2){__uint_as_float(v2.x << 16),
                                    __uint_as_float(v2.x & 0xffff0000u)};
            acc2[1] += W2 * (f32x2){__uint_as_float(v2.y << 16),
                                    __uint_as_float(v2.y & 0xffff0000u)};
            acc2[2] += W2 * (f32x2){__uint_as_float(v2.z << 16),
                                    __uint_as_float(v2.z & 0xffff0000u)};
            acc2[3] += W2 * (f32x2){__uint_as_float(v2.w << 16),
                                    __uint_as_float(v2.w & 0xffff0000u)};
            acc2[0] += W3 * (f32x2){__uint_as_float(v3.x << 16),
                                    __uint_as_float(v3.x & 0xffff0000u)};
            acc2[1] += W3 * (f32x2){__uint_as_float(v3.y << 16),
                                    __uint_as_float(v3.y & 0xffff0000u)};
            acc2[2] += W3 * (f32x2){__uint_as_float(v3.z << 16),
                                    __uint_as_float(v3.z & 0xffff0000u)};
            acc2[3] += W3 * (f32x2){__uint_as_float(v3.w << 16),
                                    __uint_as_float(v3.w & 0xffff0000u)};
        }
        __syncthreads();
    }

    // ---- cross-slice reduction ----
    #pragma unroll
    for (int n = 0; n < 4; ++n) {
        s_red[tid][2 * n]     = acc2[n].x;
        s_red[tid][2 * n + 1] = acc2[n].y;
    }
    __syncthreads();

    const int cch = tid & 31;
    float sum = 0.0f;
    #pragma unroll
    for (int s = 0; s < 8; ++s)
        sum += s_red[h * 32 + s * 4 + (cch >> 3)][cch & 7];

    slots[(size_t)q * 256 + tid] = f2bf(sum / fmaxf(cnt, 1.0f));
}

// ---------------------------------------------------------------------------
extern "C" void kernel_launch(void* const* d_in, const int* in_sizes, int n_in,
                              void* d_out, int out_size, void* d_ws, size_t ws_size,
                              hipStream_t stream) {
    const float* query   = (const float*)d_in[0];
    // d_in[1] = key : unused by the deformable-attention math
    const float* value   = (const float*)d_in[2];   // (6,5440,1,256) -> (32640,256)
    const float* refp    = (const float*)d_in[3];
    const int*   vox     = (const int*)d_in[4];
    // d_in[5] spatial_shapes, d_in[6] level_start_index : compile-time constants
    const float* value_W = (const float*)d_in[7];
    const float* value_b = (const float*)d_in[8];
    const float* off_W   = (const float*)d_in[9];
    const float* off_b   = (const float*)d_in[10];
    const float* attw_W  = (const float*)d_in[11];
    const float* attw_b  = (const float*)d_in[12];
    const float* out_W   = (const float*)d_in[13];
    const float* out_b   = (const float*)d_in[14];
    float* out = (float*)d_out;

    // ws layout (bytes), liveness-aliased:
    //   [0, 16711680)        vproj bf16 [32640][256]
    //   [16711680, 47431680) value_bf bf16 (dead after value gemm) / qkcat f32
    //   [47431680, 52551680) query_bf bf16 (dead after qk gemm) / slots bf16
    //   [52551680, ...)      value_Wt | out_Wt | qk_Wt  bf16
    char* ws = (char*)d_ws;
    ushort_t* vproj    = (ushort_t*)ws;
    ushort_t* value_bf = (ushort_t*)(ws + 16711680);
    float*    qkcat    = (float*)   (ws + 16711680);
    ushort_t* query_bf = (ushort_t*)(ws + 47431680);
    ushort_t* slots    = (ushort_t*)(ws + 47431680);
    ushort_t* value_Wt = (ushort_t*)(ws + 52551680);
    ushort_t* out_Wt   = (ushort_t*)(ws + 52551680 + 131072);
    ushort_t* qk_Wt    = (ushort_t*)(ws + 52551680 + 262144);

    // 1. prep: cvt value/query to bf16 + transpose/convert all weights
    prep_k<<<5842, 256, 0, stream>>>(value, query, value_W, out_W, off_W, attw_W,
                                     value_bf, query_bf, value_Wt, out_Wt, qk_Wt);
    // 2. value projection: 32640 x 256 x 256, bf16 out
    gemm_mfma<true, false><<<dim3(255, 2), 256, 0, stream>>>(
        value_bf, value_Wt, value_b, value_b, 256, nullptr,
        (void*)vproj, 32640, 256);
    // 3. fused offset+attw projection: 10000 x 256 x 768, f32 out
    gemm_mfma<false, false><<<dim3(79, 6), 256, 0, stream>>>(
        query_bf, qk_Wt, off_b, attw_b, 512, nullptr,
        (void*)qkcat, 10000, 768);
    // 4. deformable sampling + softmax + camera mask/count -> bf16 slots
    sample_k<<<10000, 256, 0, stream>>>(qkcat, refp, vox, vproj, slots);
    // 5. output projection + residual, f32 out
    gemm_mfma<false, true><<<dim3(79, 2), 256, 0, stream>>>(
        slots, out_Wt, out_b, out_b, 256, query, (void*)out, 10000, 256);
}